// Round 3
// baseline (825.163 us; speedup 1.0000x reference)
//
#include <hip/hip_runtime.h>
#include <hip/hip_bf16.h>
#include <stdint.h>

#define BATCH 128
#define SEQ   512
#define NW    6
#define DIM   64
#define NELEM (BATCH * SEQ * NW)   // 393216
#define PI_F  3.14159265358979323846f

// ---------------------------------------------------------------------------
// CNOT-chain gather permutations (wire 0 = MSB of the 6-bit index).
// ---------------------------------------------------------------------------
__device__ __forceinline__ int Gq(int i) {          // C01,C12,C23,C34,C45,C50
    int x = i ^ ((i & 1) << 5);
    x ^= (x >> 1) & 1;
    x ^= ((x >> 2) & 1) << 1;
    x ^= ((x >> 3) & 1) << 2;
    x ^= ((x >> 4) & 1) << 3;
    x ^= ((x >> 5) & 1) << 4;
    return x;
}
__device__ __forceinline__ int Gv(int i) {          // C01,C12,C23,C34,C45
    int x = i ^ ((i >> 1) & 1);
    x ^= ((x >> 2) & 1) << 1;
    x ^= ((x >> 3) & 1) << 2;
    x ^= ((x >> 4) & 1) << 3;
    x ^= ((x >> 5) & 1) << 4;
    return x;
}

__device__ __forceinline__ void cmul(float& dr, float& di, float ar, float ai,
                                     float br, float bi) {
    dr = ar * br - ai * bi;
    di = ar * bi + ai * br;
}

// ---------------------------------------------------------------------------
// Kernel 1: bf16-vs-f32 detection on `angles` (U(0,pi) data).
// ---------------------------------------------------------------------------
__global__ void k_detect(const uint32_t* __restrict__ a, int* __restrict__ flag) {
    __shared__ int cnt;
    if (threadIdx.x == 0) cnt = 0;
    __syncthreads();
    uint32_t w = a[threadIdx.x];
    uint32_t e = (w >> 8) & 0xFFu;
    if (e >= 0x3Au && e <= 0x41u) atomicAdd(&cnt, 1);
    __syncthreads();
    if (threadIdx.x == 0) *flag = (cnt >= 128) ? 1 : 0;   // 1 = bf16
}

__device__ __forceinline__ float ldf(const void* p, int i, bool bf) {
    if (bf) {
        uint32_t u = (uint32_t)((const uint16_t*)p)[i];
        return __uint_as_float(u << 16);
    }
    return ((const float*)p)[i];
}

// ---------------------------------------------------------------------------
// Kernel 2: inputs -> f32 ws; precompute cos/sin(x/2) of injection angles.
// cs layout: [b][t][w][2]. misc: [0..3]=poly, [4..39]=fwd, [40..75]=bwd,
// [76]=fc, [77]=bc.
// ---------------------------------------------------------------------------
__global__ void k_convert(const void* ang, const void* poly, const void* fp,
                          const void* bp, const void* fc, const void* bc,
                          float* __restrict__ cs, float* __restrict__ misc,
                          const int* __restrict__ flag) {
    const bool bf = (*flag != 0);
    const int i = blockIdx.x * blockDim.x + threadIdx.x;
    if (i < NELEM) {
        float x = ldf(ang, i, bf);
        float s, c;
        __sincosf(0.5f * x, &s, &c);
        cs[2 * i]     = c;
        cs[2 * i + 1] = s;
    }
    if (i < 4)                    misc[i]            = ldf(poly, i, bf);
    else if (i >= 64 && i < 100)  misc[4 + (i - 64)] = ldf(fp, i - 64, bf);
    else if (i >= 128 && i < 164) misc[40 + (i - 128)] = ldf(bp, i - 128, bf);
    else if (i == 200)            misc[76] = ldf(fc, 0, bf);
    else if (i == 201)            misc[77] = ldf(bc, 0, bf);
}

// ---------------------------------------------------------------------------
// Kernel 3: recurrent sim. One wave per chain, lane p = one amplitude.
// CNOT perms virtualized (GF(2)-linear); QSVT phases fused to one constant.
// NEW vs round 2: radix-8 stage fusion. Every 2-level op sequence
//   x'_p = A(p) x_p + B(p) x_{p^e}
// fused 3-at-a-time into   x'_p = sum_{m in span(e1,e2,e3)} D[m](p) x_{p^m}
// via the recurrence D'[m]=A*D[m], D'[m^e]=B*shfl_xor(D[m],e).
// Serial LDS stages per step: 4 (gates) + 2 (inject) + 2 (WHT) + 1 (gather)
// = 9, down from ~25.
// ---------------------------------------------------------------------------
__global__ void __launch_bounds__(64) k_sim(const float* __restrict__ cs,
                                            const float* __restrict__ misc,
                                            float* __restrict__ hbuf) {
    const int p     = threadIdx.x;
    const int chain = blockIdx.x;            // 0..255
    const int dir   = chain >> 7;            // 0 = fwd, 1 = bwd
    const int b     = chain & 127;
    const float* poly = misc;
    const float* prm  = misc + (dir ? 40 : 4);
    float* orow = hbuf + (size_t)dir * NELEM + (size_t)b * (SEQ * NW);
    const float* csrow_base = cs + (size_t)b * (SEQ * NW * 2);

    // ---- permutation tables (setup only) ----
    __shared__ int GIQ[DIM], GIV[DIM];
    GIQ[Gq(p)] = p;
    GIV[Gv(p)] = p;
    __syncthreads();
    const int i1 = GIQ[p], i2 = GIQ[i1], i3 = GIQ[i2], i4 = GIQ[i3];
    const int i5 = GIV[i4], i6 = GIV[i5];

    // ---- fused QSVT phase constant ----
    float Pc = 1.f, Ps = 0.f;
    {
        int pops[4];
        pops[0] = (int)__popc((unsigned)p);
        pops[1] = (int)__popc((unsigned)i1);
        pops[2] = (int)__popc((unsigned)i2);
        pops[3] = (int)__popc((unsigned)i3);
#pragma unroll
        for (int d = 0; d < 4; ++d) {
            float ang = PI_F * poly[d] * (float)(pops[d] - 3);
            float s, c;
            __sincosf(ang, &s, &c);
            float nc = Pc * c - Ps * s;
            float ns = Pc * s + Ps * c;
            Pc = nc; Ps = ns;
        }
    }

    // ---- partner XOR masks (wave-uniform; constant-folded) ----
    int E[12], E3[6];
#pragma unroll
    for (int w = 0; w < NW; ++w) {
        const int m = 1 << (5 - w);
        E[w]     = Gq(Gq(Gq(Gq(m))));                 // layer-0 frame f4
        E[6 + w] = Gq(Gq(Gq(Gq(Gv(m)))));             // layer-1 frame f5
        E3[w]    = Gq(Gq(Gq(Gq(Gv(Gv(m))))));         // injection frame f6
    }

    // ---- per-gate coefficients: C1 = U[b][b], C2 = U[b][1-b] ----
    float C1r[12], C1i[12], C2r[12], C2i[12];
#pragma unroll
    for (int g = 0; g < 12; ++g) {
        const int layer = g / 6, w = g % 6;
        float cx, sx, cy, sy, cz, sz;
        __sincosf(0.5f * prm[3 * g + 0], &sx, &cx);
        __sincosf(0.5f * prm[3 * g + 1], &sy, &cy);
        __sincosf(0.5f * prm[3 * g + 2], &sz, &cz);
        const float A = cy * cx, B = sy * sx, C = sy * cx, D = cy * sx;
        const float U00r = cz * A + sz * B, U00i = cz * B - sz * A;
        const float U11r = U00r,            U11i = sz * A - cz * B;
        const float Xr   = cz * C + sz * D, Xi   = sz * C - cz * D;
        const int fi = (layer == 0) ? i4 : i5;
        const int bb = (fi >> (5 - w)) & 1;
        C1r[g] = bb ? U11r : U00r;
        C1i[g] = bb ? U11i : U00i;
        C2r[g] = bb ? Xr : -Xr;
        C2i[g] = Xi;
    }

    // ---- fused 3-gate coefficient tables (4 groups x 8 partners) ----
    float GDr[4][8], GDi[4][8];
    int   GM[4][8];
#pragma unroll
    for (int grp = 0; grp < 4; ++grp) {
        const int g0 = grp * 3;
        const int e1 = E[g0], e2 = E[g0 + 1], e3 = E[g0 + 2];
        float d0r[2], d0i[2];
        d0r[0] = C1r[g0]; d0i[0] = C1i[g0];
        d0r[1] = C2r[g0]; d0i[1] = C2i[g0];
        float d1r[4], d1i[4];
        cmul(d1r[0], d1i[0], C1r[g0 + 1], C1i[g0 + 1], d0r[0], d0i[0]);
        cmul(d1r[1], d1i[1], C1r[g0 + 1], C1i[g0 + 1], d0r[1], d0i[1]);
        {
            float t0r = __shfl_xor(d0r[0], e2, 64), t0i = __shfl_xor(d0i[0], e2, 64);
            float t1r = __shfl_xor(d0r[1], e2, 64), t1i = __shfl_xor(d0i[1], e2, 64);
            cmul(d1r[2], d1i[2], C2r[g0 + 1], C2i[g0 + 1], t0r, t0i);
            cmul(d1r[3], d1i[3], C2r[g0 + 1], C2i[g0 + 1], t1r, t1i);
        }
#pragma unroll
        for (int m = 0; m < 4; ++m)
            cmul(GDr[grp][m], GDi[grp][m], C1r[g0 + 2], C1i[g0 + 2], d1r[m], d1i[m]);
#pragma unroll
        for (int m = 0; m < 4; ++m) {
            float tr = __shfl_xor(d1r[m], e3, 64), ti = __shfl_xor(d1i[m], e3, 64);
            cmul(GDr[grp][4 + m], GDi[grp][4 + m], C2r[g0 + 2], C2i[g0 + 2], tr, ti);
        }
#pragma unroll
        for (int m = 0; m < 8; ++m)
            GM[grp][m] = ((m & 1) ? e1 : 0) ^ ((m & 2) ? e2 : 0) ^ ((m & 4) ? e3 : 0);
    }

    // ---- injection: lane signs + fused sign combos (2 groups x 8) ----
    float SG[6];
#pragma unroll
    for (int w = 0; w < NW; ++w) SG[w] = ((i6 >> (5 - w)) & 1) ? 1.f : -1.f;
    float ISG[2][8];
    int   MI[2][8];
#pragma unroll
    for (int grp = 0; grp < 2; ++grp) {
        const int w0 = grp * 3;
        const int e1 = E3[w0], e2 = E3[w0 + 1], e3 = E3[w0 + 2];
        const float s0 = SG[w0], s1 = SG[w0 + 1], s2 = SG[w0 + 2];
        const float s0_e2  = __shfl_xor(s0, e2, 64);
        const float s0_e3  = __shfl_xor(s0, e3, 64);
        const float s1_e3  = __shfl_xor(s1, e3, 64);
        const float s0_e23 = __shfl_xor(s0, e2 ^ e3, 64);
        ISG[grp][0] = 1.f;
        ISG[grp][1] = s0;
        ISG[grp][2] = s1;
        ISG[grp][3] = s1 * s0_e2;
        ISG[grp][4] = s2;
        ISG[grp][5] = s2 * s0_e3;
        ISG[grp][6] = s2 * s1_e3;
        ISG[grp][7] = s2 * s1_e3 * s0_e23;
#pragma unroll
        for (int m = 0; m < 8; ++m)
            MI[grp][m] = ((m & 1) ? e1 : 0) ^ ((m & 2) ? e2 : 0) ^ ((m & 4) ? e3 : 0);
    }

    // ---- WHT: fused sign tables (2 groups x 8) ----
    float BS[6];
#pragma unroll
    for (int k = 0; k < 6; ++k) BS[k] = (p & (1 << k)) ? -1.f : 1.f;
    float WS[2][8];
#pragma unroll
    for (int m = 0; m < 8; ++m) {
        float a = 1.f, c = 1.f;
#pragma unroll
        for (int k = 0; k < 3; ++k)
            if (!((m >> k) & 1)) { a *= BS[k]; c *= BS[3 + k]; }
        WS[0][m] = a;
        WS[1][m] = c;
    }

    // ---- measurement extraction lanes ----
    int Lw[6] = {0, 0, 0, 0, 0, 0};
#pragma unroll
    for (int j = 0; j < 6; ++j) {
        const int f6x = GIV[GIV[GIQ[GIQ[GIQ[GIQ[1 << j]]]]]];
#pragma unroll
        for (int w = 0; w < NW; ++w)
            if ((f6x >> (5 - w)) & 1) Lw[w] |= (1 << j);
    }
    int myw = -1;
#pragma unroll
    for (int w = 0; w < NW; ++w)
        if (Lw[w] == p) myw = w;

    // ---- encode selection bits (f0 = identity) ----
    bool EB[6];
#pragma unroll
    for (int w = 0; w < NW; ++w) EB[w] = (p >> (5 - w)) & 1;

    // =======================  recurrent loop  =======================
    float h[6] = {0.f, 0.f, 0.f, 0.f, 0.f, 0.f};
    // prefetch injection sincos for t=0
    int tin0 = dir ? (SEQ - 1) : 0;
    const float4* xrp = (const float4*)(csrow_base + tin0 * (NW * 2));
    float4 xq0 = xrp[0], xq1 = xrp[1], xq2 = xrp[2];

    for (int t = 0; t < SEQ; ++t) {
        const int tin = dir ? (SEQ - 1 - t) : t;
        // prefetch next step's injection sincos (hides global-load latency)
        int tn = t + 1 < SEQ ? t + 1 : t;
        int tinn = dir ? (SEQ - 1 - tn) : tn;
        const float4* xnp = (const float4*)(csrow_base + tinn * (NW * 2));
        float4 nx0 = xnp[0], nx1 = xnp[1], nx2 = xnp[2];

        // injection uniform products (independent of psi -> overlaps gates)
        float U[2][8];
        {
            const float ca = xq0.x, sa = xq0.y, cb = xq0.z, sb = xq0.w;
            const float cc = xq1.x, sc = xq1.y;
            const float t00 = ca * cb, t10 = sa * cb, t01 = ca * sb, t11 = sa * sb;
            U[0][0] = t00 * cc; U[0][1] = t10 * cc; U[0][2] = t01 * cc; U[0][3] = t11 * cc;
            U[0][4] = t00 * sc; U[0][5] = t10 * sc; U[0][6] = t01 * sc; U[0][7] = t11 * sc;
        }
        {
            const float ca = xq1.z, sa = xq1.w, cb = xq2.x, sb = xq2.y;
            const float cc = xq2.z, sc = xq2.w;
            const float t00 = ca * cb, t10 = sa * cb, t01 = ca * sb, t11 = sa * sb;
            U[1][0] = t00 * cc; U[1][1] = t10 * cc; U[1][2] = t01 * cc; U[1][3] = t11 * cc;
            U[1][4] = t00 * sc; U[1][5] = t10 * sc; U[1][6] = t01 * sc; U[1][7] = t11 * sc;
        }

        // 1) product-state encode (+ fused QSVT phase)
        float amp = 1.f;
#pragma unroll
        for (int w = 0; w < NW; ++w) {
            float s, c;
            __sincosf(0.5f * h[w], &s, &c);
            amp *= EB[w] ? s : c;
        }
        float re = amp * Pc;
        float im = amp * Ps;

        // 2) variational gates: 4 fused radix-8 stages
#pragma unroll
        for (int grp = 0; grp < 4; ++grp) {
            float xr_[8], xi_[8];
            xr_[0] = re; xi_[0] = im;
#pragma unroll
            for (int m = 1; m < 8; ++m) {
                xr_[m] = __shfl_xor(re, GM[grp][m], 64);
                xi_[m] = __shfl_xor(im, GM[grp][m], 64);
            }
            float nr = 0.f, ni = 0.f;
#pragma unroll
            for (int m = 0; m < 8; ++m) {
                nr += GDr[grp][m] * xr_[m] - GDi[grp][m] * xi_[m];
                ni += GDr[grp][m] * xi_[m] + GDi[grp][m] * xr_[m];
            }
            re = nr; im = ni;
        }

        // 3) injection: 2 fused radix-8 stages (real coefficients)
#pragma unroll
        for (int grp = 0; grp < 2; ++grp) {
            float d[8];
#pragma unroll
            for (int m = 0; m < 8; ++m) d[m] = ISG[grp][m] * U[grp][m];
            float xr_[8], xi_[8];
            xr_[0] = re; xi_[0] = im;
#pragma unroll
            for (int m = 1; m < 8; ++m) {
                xr_[m] = __shfl_xor(re, MI[grp][m], 64);
                xi_[m] = __shfl_xor(im, MI[grp][m], 64);
            }
            float nr = 0.f, ni = 0.f;
#pragma unroll
            for (int m = 0; m < 8; ++m) {
                nr += d[m] * xr_[m];
                ni += d[m] * xi_[m];
            }
            re = nr; im = ni;
        }

        // 4) WHT: 2 fused radix-8 stages
        float q = re * re + im * im;
#pragma unroll
        for (int grp = 0; grp < 2; ++grp) {
            float pq[8];
            pq[0] = q;
#pragma unroll
            for (int m = 1; m < 8; ++m)
                pq[m] = __shfl_xor(q, grp ? (m << 3) : m, 64);
            float nq = 0.f;
#pragma unroll
            for (int m = 0; m < 8; ++m) nq += WS[grp][m] * pq[m];
            q = nq;
        }

        // 5) store + gather next h
        if (myw >= 0) orow[tin * NW + myw] = q;
#pragma unroll
        for (int w = 0; w < NW; ++w) h[w] = __shfl(q, Lw[w], 64);

        xq0 = nx0; xq1 = nx1; xq2 = nx2;
    }
}

// ---------------------------------------------------------------------------
// Kernel 4: out = sigmoid(fc)*h_fwd + sigmoid(bc)*h_bwd, dtype per flag.
// ---------------------------------------------------------------------------
__global__ void k_combine(const float* __restrict__ hbuf,
                          const float* __restrict__ misc,
                          void* __restrict__ out, const int* __restrict__ flag) {
    const int i = blockIdx.x * blockDim.x + threadIdx.x;
    if (i >= NELEM) return;
    const float sf = 1.f / (1.f + __expf(-misc[76]));
    const float sb = 1.f / (1.f + __expf(-misc[77]));
    const float v = sf * hbuf[i] + sb * hbuf[NELEM + i];
    if (*flag) ((__hip_bfloat16*)out)[i] = __float2bfloat16(v);
    else       ((float*)out)[i] = v;
}

// ---------------------------------------------------------------------------
extern "C" void kernel_launch(void* const* d_in, const int* in_sizes, int n_in,
                              void* d_out, int out_size, void* d_ws, size_t ws_size,
                              hipStream_t stream) {
    const void* ang  = d_in[0];
    const void* poly = d_in[1];
    const void* fp   = d_in[2];
    const void* bp   = d_in[3];
    const void* fc   = d_in[4];
    const void* bc   = d_in[5];

    // ws layout (floats): cs[2*NELEM] | misc[128] | hbuf[2*NELEM] | flag
    float* cs   = (float*)d_ws;
    float* misc = cs + 2 * NELEM;
    float* hbuf = misc + 128;
    int*   flag = (int*)(hbuf + 2 * NELEM);

    k_detect<<<1, 256, 0, stream>>>((const uint32_t*)ang, flag);
    k_convert<<<(NELEM + 255) / 256, 256, 0, stream>>>(ang, poly, fp, bp, fc, bc,
                                                       cs, misc, flag);
    k_sim<<<256, 64, 0, stream>>>(cs, misc, hbuf);
    k_combine<<<(NELEM + 255) / 256, 256, 0, stream>>>(hbuf, misc, d_out, flag);
}

// Round 4
// 548.960 us; speedup vs baseline: 1.5031x; 1.5031x over previous
//
#include <hip/hip_runtime.h>
#include <hip/hip_bf16.h>
#include <stdint.h>

#define BATCH 128
#define SEQ   512
#define NW    6
#define DIM   64
#define NELEM (BATCH * SEQ * NW)   // 393216
#define PI_F  3.14159265358979323846f

// ---------------------------------------------------------------------------
// DPP wave-64 sum: row_shr 1/2/4/8 + row_bcast15 + row_bcast31, total in
// lane 63, broadcast via readlane (VALU pipe only, no LDS).
// ---------------------------------------------------------------------------
#define DPP_ADD(x, ctrl) \
    ((x) + __int_as_float(__builtin_amdgcn_update_dpp( \
        0, __float_as_int(x), (ctrl), 0xF, 0xF, false)))

__device__ __forceinline__ float wave_sum64(float v) {
    v = DPP_ADD(v, 0x111);   // row_shr:1
    v = DPP_ADD(v, 0x112);   // row_shr:2
    v = DPP_ADD(v, 0x114);   // row_shr:4
    v = DPP_ADD(v, 0x118);   // row_shr:8
    v = DPP_ADD(v, 0x142);   // row_bcast:15
    v = DPP_ADD(v, 0x143);   // row_bcast:31
    return __int_as_float(__builtin_amdgcn_readlane(__float_as_int(v), 63));
}

// ---------------------------------------------------------------------------
// Kernel 1: bf16-vs-f32 detection on `angles` (U(0,pi) data).
// ---------------------------------------------------------------------------
__global__ void k_detect(const uint32_t* __restrict__ a, int* __restrict__ flag) {
    __shared__ int cnt;
    if (threadIdx.x == 0) cnt = 0;
    __syncthreads();
    uint32_t w = a[threadIdx.x];
    uint32_t e = (w >> 8) & 0xFFu;
    if (e >= 0x3Au && e <= 0x41u) atomicAdd(&cnt, 1);
    __syncthreads();
    if (threadIdx.x == 0) *flag = (cnt >= 128) ? 1 : 0;   // 1 = bf16
}

__device__ __forceinline__ float ldf(const void* p, int i, bool bf) {
    if (bf) {
        uint32_t u = (uint32_t)((const uint16_t*)p)[i];
        return __uint_as_float(u << 16);
    }
    return ((const float*)p)[i];
}

// ---------------------------------------------------------------------------
// Kernel 2: inputs -> f32 ws; precompute cos(x), sin(x) (FULL angle — used by
// the observable-rotation identity) for every injection angle.
// cs layout: [b][t][w][2]. misc: [0..3]=poly, [4..39]=fwd, [40..75]=bwd,
// [76]=fc, [77]=bc.
// ---------------------------------------------------------------------------
__global__ void k_convert(const void* ang, const void* poly, const void* fp,
                          const void* bp, const void* fc, const void* bc,
                          float* __restrict__ cs, float* __restrict__ misc,
                          const int* __restrict__ flag) {
    const bool bf = (*flag != 0);
    const int i = blockIdx.x * blockDim.x + threadIdx.x;
    if (i < NELEM) {
        float x = ldf(ang, i, bf);
        float s, c;
        __sincosf(x, &s, &c);
        cs[2 * i]     = c;
        cs[2 * i + 1] = s;
    }
    if (i < 4)                    misc[i]            = ldf(poly, i, bf);
    else if (i >= 64 && i < 100)  misc[4 + (i - 64)] = ldf(fp, i - 64, bf);
    else if (i >= 128 && i < 164) misc[40 + (i - 128)] = ldf(bp, i - 128, bf);
    else if (i == 200)            misc[76] = ldf(fc, 0, bf);
    else if (i == 201)            misc[77] = ldf(bc, 0, bf);
}

// ---------------------------------------------------------------------------
// Kernel 3: precompute M[dir] = (chain CNOTs · layer2) · (chain CNOTs ·
// layer1) · prod_d(ring CNOTs · phase_d)  as an explicit 64x64 complex
// matrix, by evolving each basis column. One block per (dir, col); lane p =
// amplitude p. Perf-irrelevant (runs once per launch).
// Mg layout: [dir][row][col][2] floats.
// ---------------------------------------------------------------------------
__global__ void __launch_bounds__(64) k_msetup(const float* __restrict__ misc,
                                               float* __restrict__ Mg) {
    const int p   = threadIdx.x;
    const int col = blockIdx.x & 63;
    const int dir = blockIdx.x >> 6;
    const float* poly = misc;
    const float* prm  = misc + (dir ? 40 : 4);

    float yr = (p == col) ? 1.f : 0.f;
    float yi = 0.f;

    // QSVT: 4 x (diag phase, ring CNOTs (0,1)(1,2)(2,3)(3,4)(4,5)(5,0))
#pragma unroll
    for (int d = 0; d < 4; ++d) {
        const float th = 0.5f * PI_F * poly[d] *
                         (float)(6 - 2 * (int)__popc((unsigned)p));
        float s, c;
        __sincosf(th, &s, &c);                 // multiply by e^{-i th}
        const float nr = yr * c + yi * s;
        const float ni = yi * c - yr * s;
        yr = nr; yi = ni;
#pragma unroll
        for (int k = 0; k < 6; ++k) {
            const int cw = k, tw = (k + 1) % 6;
            const int src = p ^ (((p >> (5 - cw)) & 1) << (5 - tw));
            yr = __shfl(yr, src, 64);
            yi = __shfl(yi, src, 64);
        }
    }

    // variational layers: 6 single-qubit gates then chain CNOTs, x2
    int idx = 0;
#pragma unroll
    for (int l = 0; l < 2; ++l) {
#pragma unroll
        for (int w = 0; w < 6; ++w) {
            float cx, sx, cy, sy, cz, sz;
            __sincosf(0.5f * prm[idx + 0], &sx, &cx);
            __sincosf(0.5f * prm[idx + 1], &sy, &cy);
            __sincosf(0.5f * prm[idx + 2], &sz, &cz);
            idx += 3;
            const float A = cy * cx, B = sy * sx, C = sy * cx, D = cy * sx;
            const float U00r = cz * A + sz * B, U00i = cz * B - sz * A;
            const float U11r = U00r,            U11i = sz * A - cz * B;
            const float Xr   = cz * C + sz * D, Xi   = sz * C - cz * D;
            const int m  = 1 << (5 - w);
            const int bb = (p >> (5 - w)) & 1;
            const float C1r = bb ? U11r : U00r;
            const float C1i = bb ? U11i : U00i;
            const float C2r = bb ? Xr : -Xr;
            const float C2i = Xi;
            const float pr = __shfl_xor(yr, m, 64);
            const float pi = __shfl_xor(yi, m, 64);
            const float nr = C1r * yr - C1i * yi + C2r * pr - C2i * pi;
            const float ni = C1r * yi + C1i * yr + C2r * pi + C2i * pr;
            yr = nr; yi = ni;
        }
#pragma unroll
        for (int k = 0; k < 5; ++k) {
            const int src = p ^ (((p >> (5 - k)) & 1) << (5 - (k + 1)));
            yr = __shfl(yr, src, 64);
            yi = __shfl(yi, src, 64);
        }
    }

    float* out = Mg + ((size_t)(dir * 64 + p) * 64 + (size_t)col) * 2;
    out[0] = yr;
    out[1] = yi;
}

// ---------------------------------------------------------------------------
// Kernel 4: recurrent sim. One wave per chain; lane p = one amplitude (pure
// logical index — no frame bookkeeping). Per step:
//   psi0 = real product state from h  (6 sincos, no shuffles)
//   psi' = M psi0  — M rows in VGPRs, x broadcast via uniform ds_read_b128
//   z_w  = cos(x_w) <Z_w> - sin(x_w) <X_w>   (injection folded into the
//          observable: RY(x)^dag Z RY(x) = cos x Z - sin x X)
//   <Z_w>: sign-flipped |psi'|^2, <X_w>: one shfl_xor pair per wire.
//   Reductions via DPP on the VALU pipe (no LDS).
// Per-step bpermutes: 12 (was 48 in r2, 104 in r3).
// ---------------------------------------------------------------------------
__global__ void __launch_bounds__(64, 1) k_sim(const float* __restrict__ cs,
                                               const float* __restrict__ Mg,
                                               float* __restrict__ hbuf) {
    const int p     = threadIdx.x;
    const int chain = blockIdx.x;            // 0..255
    const int dir   = chain >> 7;
    const int b     = chain & 127;
    float* orow = hbuf + (size_t)dir * NELEM + (size_t)b * (SEQ * NW);
    const float* csrow = cs + (size_t)b * (SEQ * NW * 2);

    // my row of M: 64 complex = 32 float4 in VGPRs
    float4 M[32];
    {
        const float4* mrow = (const float4*)(Mg + (size_t)(dir * 64 + p) * 128);
#pragma unroll
        for (int k = 0; k < 32; ++k) M[k] = mrow[k];
    }

    __shared__ float xs[2][DIM];             // ping-pong x buffer (512 B)

    int zmask[6];
#pragma unroll
    for (int w = 0; w < 6; ++w) zmask[w] = ((p >> (5 - w)) & 1) << 31;
    bool EB[6];
#pragma unroll
    for (int w = 0; w < 6; ++w) EB[w] = (p >> (5 - w)) & 1;

    float h[6] = {0.f, 0.f, 0.f, 0.f, 0.f, 0.f};

    const int tin0 = dir ? SEQ - 1 : 0;
    const float4* x0p = (const float4*)(csrow + tin0 * 12);
    float4 xq0 = x0p[0], xq1 = x0p[1], xq2 = x0p[2];

    for (int t = 0; t < SEQ; ++t) {
        const int tin  = dir ? (SEQ - 1 - t) : t;
        const int tn   = (t + 1 < SEQ) ? t + 1 : t;
        const int tinn = dir ? (SEQ - 1 - tn) : tn;
        const float4* xnp = (const float4*)(csrow + tinn * 12);
        float4 nx0 = xnp[0], nx1 = xnp[1], nx2 = xnp[2];

        // 1) encode: real product state
        float amp = 1.f;
#pragma unroll
        for (int w = 0; w < 6; ++w) {
            float s, c;
            __sincosf(0.5f * h[w], &s, &c);
            amp *= EB[w] ? s : c;
        }
        float* xb = xs[t & 1];
        xb[p] = amp;
        __syncthreads();                     // RAW; WAR safe via ping-pong

        // 2) matvec y = M x (x real, broadcast reads on LDS pipe)
        float yr = 0.f, yi = 0.f, zr = 0.f, zi = 0.f;
#pragma unroll
        for (int j = 0; j < 16; ++j) {
            const float4 xv = *(const float4*)(xb + 4 * j);   // uniform addr
            yr += xv.x * M[2 * j].x;     yi += xv.x * M[2 * j].y;
            zr += xv.y * M[2 * j].z;     zi += xv.y * M[2 * j].w;
            yr += xv.z * M[2 * j + 1].x; yi += xv.z * M[2 * j + 1].y;
            zr += xv.w * M[2 * j + 1].z; zi += xv.w * M[2 * j + 1].w;
        }
        yr += zr; yi += zi;

        // 3) measurement with injection folded into the observable
        const float q = yr * yr + yi * yi;
        float cxw[6], sxw[6];
        cxw[0] = xq0.x; sxw[0] = xq0.y; cxw[1] = xq0.z; sxw[1] = xq0.w;
        cxw[2] = xq1.x; sxw[2] = xq1.y; cxw[3] = xq1.z; sxw[3] = xq1.w;
        cxw[4] = xq2.x; sxw[4] = xq2.y; cxw[5] = xq2.z; sxw[5] = xq2.w;

        float tsum[6];
#pragma unroll
        for (int w = 0; w < 6; ++w) {
            const int m = 1 << (5 - w);
            const float pr = __shfl_xor(yr, m, 64);
            const float pi = __shfl_xor(yi, m, 64);
            const float ac = yr * pr + yi * pi;   // per-lane <X_w> contrib
            const float sq = __int_as_float(__float_as_int(q) ^ zmask[w]);
            tsum[w] = cxw[w] * sq - sxw[w] * ac;
        }

        // 4) six DPP wave-reductions -> uniform next-h
#pragma unroll
        for (int w = 0; w < 6; ++w) h[w] = wave_sum64(tsum[w]);

        // 5) store z (lanes 0..5)
        float ov = h[0];
#pragma unroll
        for (int w = 1; w < 6; ++w) ov = (p == w) ? h[w] : ov;
        if (p < 6) orow[tin * NW + p] = ov;

        xq0 = nx0; xq1 = nx1; xq2 = nx2;
    }
}

// ---------------------------------------------------------------------------
// Kernel 5: out = sigmoid(fc)*h_fwd + sigmoid(bc)*h_bwd, dtype per flag.
// ---------------------------------------------------------------------------
__global__ void k_combine(const float* __restrict__ hbuf,
                          const float* __restrict__ misc,
                          void* __restrict__ out, const int* __restrict__ flag) {
    const int i = blockIdx.x * blockDim.x + threadIdx.x;
    if (i >= NELEM) return;
    const float sf = 1.f / (1.f + __expf(-misc[76]));
    const float sb = 1.f / (1.f + __expf(-misc[77]));
    const float v = sf * hbuf[i] + sb * hbuf[NELEM + i];
    if (*flag) ((__hip_bfloat16*)out)[i] = __float2bfloat16(v);
    else       ((float*)out)[i] = v;
}

// ---------------------------------------------------------------------------
extern "C" void kernel_launch(void* const* d_in, const int* in_sizes, int n_in,
                              void* d_out, int out_size, void* d_ws, size_t ws_size,
                              hipStream_t stream) {
    const void* ang  = d_in[0];
    const void* poly = d_in[1];
    const void* fp   = d_in[2];
    const void* bp   = d_in[3];
    const void* fc   = d_in[4];
    const void* bc   = d_in[5];

    // ws (floats): cs[2*NELEM] | misc[128] | hbuf[2*NELEM] | M[16384] | flag
    float* cs   = (float*)d_ws;
    float* misc = cs + 2 * NELEM;
    float* hbuf = misc + 128;
    float* Mg   = hbuf + 2 * NELEM;
    int*   flag = (int*)(Mg + 2 * 64 * 64 * 2);
    // total ~6.36 MB

    k_detect<<<1, 256, 0, stream>>>((const uint32_t*)ang, flag);
    k_convert<<<(NELEM + 255) / 256, 256, 0, stream>>>(ang, poly, fp, bp, fc, bc,
                                                       cs, misc, flag);
    k_msetup<<<128, 64, 0, stream>>>(misc, Mg);
    k_sim<<<256, 64, 0, stream>>>(cs, Mg, hbuf);
    k_combine<<<(NELEM + 255) / 256, 256, 0, stream>>>(hbuf, misc, d_out, flag);
}